// Round 7
// baseline (188.924 us; speedup 1.0000x reference)
//
#include <hip/hip_runtime.h>
#include <math.h>

#define N 4096
#define DIN 512
#define D 32
#define JC 8

// ---------------- encoder: x[4096,512] -> latent[4096,32] + normed rows, fused ----------------
// R6: k-split layer 1 (w1 read once per block; partials reduced via LDS). Left top-5.
__global__ __launch_bounds__(256) void enc_kernel(
    const float* __restrict__ x,
    const float* __restrict__ w1, const float* __restrict__ b1,
    const float* __restrict__ w2, const float* __restrict__ b2,
    const float* __restrict__ w3, const float* __restrict__ b3,
    float* __restrict__ latent, float* __restrict__ normed) {
  __shared__ float xs[8][512];       // 16 KB
  __shared__ float h1p[4][8][128];   // 16 KB layer-1 partials (per k-quarter)
  __shared__ float h1s[8][128];      // 4 KB
  __shared__ float h2s[8][64];       // 2 KB
  __shared__ float w2s[128][64];     // 32 KB
  __shared__ float w3s[64][32];      // 8 KB   -> total 78 KB = 2 blocks/CU
  const int t = threadIdx.x;
  const int r0 = blockIdx.x * 8;

  // stage x rows + w2 + w3 into LDS (one barrier covers all)
  const float4* xg = (const float4*)(x + (size_t)r0 * DIN);
  float4* xl = (float4*)&xs[0][0];
#pragma unroll
  for (int i = 0; i < 4; ++i) xl[t + i * 256] = xg[t + i * 256];
  float4* w2l = (float4*)&w2s[0][0];
  const float4* w2g = (const float4*)w2;
#pragma unroll
  for (int i = 0; i < 8; ++i) w2l[t + i * 256] = w2g[t + i * 256];
  float4* w3l = (float4*)&w3s[0][0];
  const float4* w3g = (const float4*)w3;
#pragma unroll
  for (int i = 0; i < 2; ++i) w3l[t + i * 256] = w3g[t + i * 256];
  __syncthreads();

  // layer 1: 512 -> 128. wave kq handles its k-quarter for all 8 rows x 2 cols.
  {
    const int jc2 = (t & 63) * 2;
    const int kq = t >> 6;
    const int kb = kq * 128;
    float a0[8], a1[8];
#pragma unroll
    for (int r = 0; r < 8; ++r) { a0[r] = 0.f; a1[r] = 0.f; }
    const float* wp = w1 + (size_t)kb * 128 + jc2;

#define ENC_LD4(P0, P1, P2, P3, KK)                          \
    P0 = *(const float2*)&wp[(size_t)(KK) * 128];            \
    P1 = *(const float2*)&wp[(size_t)((KK) + 1) * 128];      \
    P2 = *(const float2*)&wp[(size_t)((KK) + 2) * 128];      \
    P3 = *(const float2*)&wp[(size_t)((KK) + 3) * 128];

#define ENC_STEP(W0, WA, WB, WC, KK)                                   \
    {                                                                  \
      _Pragma("unroll")                                                \
      for (int r = 0; r < 8; ++r) {                                    \
        const float4 xv = *(const float4*)&xs[r][kb + (KK)];           \
        a0[r] = fmaf(xv.x, W0.x, a0[r]); a1[r] = fmaf(xv.x, W0.y, a1[r]); \
        a0[r] = fmaf(xv.y, WA.x, a0[r]); a1[r] = fmaf(xv.y, WA.y, a1[r]); \
        a0[r] = fmaf(xv.z, WB.x, a0[r]); a1[r] = fmaf(xv.z, WB.y, a1[r]); \
        a0[r] = fmaf(xv.w, WC.x, a0[r]); a1[r] = fmaf(xv.w, WC.y, a1[r]); \
      }                                                                \
    }

    float2 A0, A1, A2, A3, B0, B1, B2, B3, C0, C1, C2, C3, D0, D1, D2, D3;
    ENC_LD4(A0, A1, A2, A3, 0)
    ENC_LD4(B0, B1, B2, B3, 4)
    ENC_LD4(C0, C1, C2, C3, 8)
    ENC_LD4(D0, D1, D2, D3, 12)
    for (int kk = 0; kk < 128; kk += 16) {
      ENC_STEP(A0, A1, A2, A3, kk + 0);
      if (kk + 16 < 128) { ENC_LD4(A0, A1, A2, A3, kk + 16) }
      ENC_STEP(B0, B1, B2, B3, kk + 4);
      if (kk + 20 < 128) { ENC_LD4(B0, B1, B2, B3, kk + 20) }
      ENC_STEP(C0, C1, C2, C3, kk + 8);
      if (kk + 24 < 128) { ENC_LD4(C0, C1, C2, C3, kk + 24) }
      ENC_STEP(D0, D1, D2, D3, kk + 12);
      if (kk + 28 < 128) { ENC_LD4(D0, D1, D2, D3, kk + 28) }
    }
#undef ENC_STEP
#undef ENC_LD4
#pragma unroll
    for (int r = 0; r < 8; ++r) {
      h1p[kq][r][jc2] = a0[r];
      h1p[kq][r][jc2 + 1] = a1[r];
    }
  }
  __syncthreads();

  // reduce the 4 k-quarter partials + bias + relu (1024 outputs)
#pragma unroll
  for (int e0 = 0; e0 < 1024; e0 += 256) {
    const int e = e0 + t;
    const int r = e >> 7, c = e & 127;
    const float s = b1[c] + ((h1p[0][r][c] + h1p[1][r][c]) + (h1p[2][r][c] + h1p[3][r][c]));
    h1s[r][c] = fmaxf(s, 0.f);
  }
  __syncthreads();

  // layer 2: 128 -> 64, relu. weights from LDS (w2s), h1 broadcast reads
  {
    const int j = t & 63, rg = t >> 6;
    const int ra = rg * 2, rb = ra + 1;
    float a0 = b2[j], a1 = b2[j];
#pragma unroll 8
    for (int kk = 0; kk < 128; ++kk) {
      const float w = w2s[kk][j];
      a0 = fmaf(h1s[ra][kk], w, a0);
      a1 = fmaf(h1s[rb][kk], w, a1);
    }
    h2s[ra][j] = fmaxf(a0, 0.f);
    h2s[rb][j] = fmaxf(a1, 0.f);
  }
  __syncthreads();

  // layer 3: 64 -> 32 + fused row-normalize (shfl reduce over the 32 j-lanes)
  {
    const int j = t & 31, og = t >> 5;  // 8 rows, 1 per group
    float acc = b3[j];
#pragma unroll 8
    for (int kk = 0; kk < 64; ++kk) acc = fmaf(h2s[og][kk], w3s[kk][j], acc);
    float s2 = acc * acc;
    s2 += __shfl_xor(s2, 1);
    s2 += __shfl_xor(s2, 2);
    s2 += __shfl_xor(s2, 4);
    s2 += __shfl_xor(s2, 8);
    s2 += __shfl_xor(s2, 16);
    const float inv = 1.0f / (sqrtf(s2) + 1e-12f);
    const size_t off = (size_t)(r0 + og) * D + j;
    latent[off] = acc;
    normed[off] = acc * inv;
  }
}

// ---------------- graph pool partials: block (bi, bj) covers 64 i-rows x 512 j ----------------
__global__ __launch_bounds__(256) void pool_kernel(const float* __restrict__ normed,
                                                   const float* __restrict__ latent,
                                                   float* __restrict__ pacc,
                                                   float* __restrict__ pdeg) {
  __shared__ float smem[8192 + 256];
  float* nt = smem;
  float* lt = smem + 4096;
  float* degr = smem + 8192;
  const int t = threadIdx.x;
  const int il = t & 63, g = t >> 6;
  const int i0 = blockIdx.x * 64;
  const int j0 = blockIdx.y * 512;

  float ni[32];
  const float* nrow = normed + (size_t)(i0 + il) * D;
#pragma unroll
  for (int c = 0; c < 32; ++c) ni[c] = nrow[c];

  float acc[32];
#pragma unroll
  for (int c = 0; c < 32; ++c) acc[c] = 0.f;
  float deg = 0.f;

  for (int jt = j0; jt < j0 + 512; jt += 128) {
    __syncthreads();
    const float4* ng = (const float4*)(normed + (size_t)jt * D);
    const float4* lg = (const float4*)(latent + (size_t)jt * D);
    float4* ntl = (float4*)nt;
    float4* ltl = (float4*)lt;
#pragma unroll
    for (int i = 0; i < 4; ++i) {
      ntl[t + i * 256] = ng[t + i * 256];
      ltl[t + i * 256] = lg[t + i * 256];
    }
    __syncthreads();
    for (int jj = g; jj < 128; jj += 4) {
      const float* nr = nt + jj * 32;
      float s = 0.f;
#pragma unroll
      for (int c = 0; c < 32; ++c) s = fmaf(ni[c], nr[c], s);
      if (s >= 0.9f) {
        deg += 1.f;
        const float* lrow = lt + jj * 32;
#pragma unroll
        for (int c = 0; c < 32; ++c) acc[c] += lrow[c];
      }
    }
  }
  __syncthreads();
  float* accr = smem;
#pragma unroll
  for (int c = 0; c < 32; ++c) accr[(g * 64 + il) * 32 + c] = acc[c];
  degr[t] = deg;
  __syncthreads();
  for (int e = t; e < 64 * 32; e += 256) {
    const float s = accr[e] + accr[2048 + e] + accr[4096 + e] + accr[6144 + e];
    pacc[((size_t)blockIdx.y * N + i0 + (e >> 5)) * 32 + (e & 31)] = s;
  }
  if (t < 64) {
    pdeg[(size_t)blockIdx.y * N + i0 + t] = degr[t] + degr[64 + t] + degr[128 + t] + degr[192 + t];
  }
}

// ---------------- combine pool partials -> h = latent + (mask@latent)/deg ----------------
__global__ __launch_bounds__(256) void pool_combine(const float* __restrict__ latent,
                                                    const float* __restrict__ pacc,
                                                    const float* __restrict__ pdeg,
                                                    float* __restrict__ h) {
  const int e = blockIdx.x * 256 + threadIdx.x;
  const int i = e >> 5;
  float s = 0.f, dg = 0.f;
#pragma unroll
  for (int gch = 0; gch < JC; ++gch) {
    s += pacc[(size_t)gch * N * 32 + e];
    dg += pdeg[(size_t)gch * N + i];
  }
  h[e] = latent[e] + s / dg;
}

// ---------------- fused QKV projection (q pre-scaled by log2e/sqrt(8)) + k-norm max ----------------
__global__ __launch_bounds__(256) void qkv_kernel(
    const float* __restrict__ h,
    const float* __restrict__ wq, const float* __restrict__ bq,
    const float* __restrict__ wk, const float* __restrict__ bk,
    const float* __restrict__ wv, const float* __restrict__ bv,
    float* __restrict__ q, float* __restrict__ k, float* __restrict__ v,
    int* __restrict__ kmax2i) {
  __shared__ float hs[32][32];
  __shared__ float wsm[3][32][32];
  __shared__ int kred[4];
  const int t = threadIdx.x;
  const int r0 = blockIdx.x * 32;
  if (t < 4) kred[t] = 0;
  ((float4*)&hs[0][0])[t] = ((const float4*)(h + (size_t)r0 * 32))[t];
  ((float4*)&wsm[0][0][0])[t] = ((const float4*)wq)[t];
  ((float4*)&wsm[1][0][0])[t] = ((const float4*)wk)[t];
  ((float4*)&wsm[2][0][0])[t] = ((const float4*)wv)[t];
  __syncthreads();
  const int j = t & 31, og = t >> 5;
  const int head = j >> 3;
  float aq[4], ak[4], av[4];
#pragma unroll
  for (int u = 0; u < 4; ++u) { aq[u] = bq[j]; ak[u] = bk[j]; av[u] = bv[j]; }
  for (int kk = 0; kk < 32; ++kk) {
    const float wqv = wsm[0][kk][j], wkv = wsm[1][kk][j], wvv = wsm[2][kk][j];
#pragma unroll
    for (int u = 0; u < 4; ++u) {
      const float hh = hs[og * 4 + u][kk];
      aq[u] = fmaf(hh, wqv, aq[u]);
      ak[u] = fmaf(hh, wkv, ak[u]);
      av[u] = fmaf(hh, wvv, av[u]);
    }
  }
  const float scale = 1.4426950408889634f * 0.35355339059327373f;  // log2(e)/sqrt(8)
#pragma unroll
  for (int u = 0; u < 4; ++u) {
    const size_t off = (size_t)(r0 + og * 4 + u) * 32 + j;
    q[off] = aq[u] * scale;
    k[off] = ak[u];
    v[off] = av[u];
  }
  // per-(row,head) ||k8||^2 via shfl over the 8 lanes of this head; block-max; global atomicMax
#pragma unroll
  for (int u = 0; u < 4; ++u) {
    float s2 = ak[u] * ak[u];
    s2 += __shfl_xor(s2, 1);
    s2 += __shfl_xor(s2, 2);
    s2 += __shfl_xor(s2, 4);
    if ((j & 7) == 0) atomicMax(&kred[head], __float_as_int(s2));
  }
  __syncthreads();
  if (t < 4) atomicMax(&kmax2i[t], kred[t]);
}

// ---------------- attention partials: block (rowBlk, jChunk); 64 rows x 512 j ----------------
// R7: double-buffered LDS tiles (16->32 KB) -> ONE barrier per tile (was 2; 16->8
// barriers/kernel). Iter t: issue global loads for t+1, compute buf[p] (hides the load
// latency), ds_write t+1 into buf[p^1] (loads returned by then), single barrier (publishes
// buf[p^1] AND protects buf[p] before its overwrite next iter). Plus a manual 1-deep
// software pipeline of the per-it LDS reads (fetch it+1's 4 b128 before it's u-loop) so
// the ~120 cyc ds_read latency overlaps the 76-instr fma block. unroll 2 retained (full
// unroll -> hoist-spill, R4). +~48 VGPR, inside the waves_per_eu(2,2) 256 budget.
// Math and per-row FP order unchanged.
__global__ __launch_bounds__(256) __attribute__((amdgpu_waves_per_eu(2, 2)))
void attn_kernel(const float* __restrict__ q,
                 const float* __restrict__ k,
                 const float* __restrict__ v,
                 const int* __restrict__ kmax2i,
                 float* __restrict__ apacc,
                 float* __restrict__ apl) {
  __shared__ float4 tiles[2048];  // buf0: kls[512]|vls[512]; buf1: kls[512]|vls[512]
  const int t = threadIdx.x;
  const int jg = t & 7, head = (t >> 3) & 3, rg = t >> 5;
  const int r0 = blockIdx.x * 64;
  const int j0 = blockIdx.y * (N / JC);

  const float km2 = __int_as_float(kmax2i[head]);

  float4 qa[8], qb[8], accA[8], accB[8];
  float mneg[8], l[8];
#pragma unroll
  for (int u = 0; u < 8; ++u) {
    const float* qr = q + (size_t)(r0 + rg * 8 + u) * 32 + head * 8;
    qa[u] = ((const float4*)qr)[0];
    qb[u] = ((const float4*)qr)[1];
    const float qn2 = qa[u].x * qa[u].x + qa[u].y * qa[u].y + qa[u].z * qa[u].z + qa[u].w * qa[u].w +
                      qb[u].x * qb[u].x + qb[u].y * qb[u].y + qb[u].z * qb[u].z + qb[u].w * qb[u].w;
    mneg[u] = -sqrtf(qn2 * km2);
    l[u] = 0.f;
    accA[u] = make_float4(0.f, 0.f, 0.f, 0.f);
    accB[u] = make_float4(0.f, 0.f, 0.f, 0.f);
  }

  // precomputed swizzle slots for the two staged quarters
  const int rA = t >> 3, slotA = (t & 7) ^ (rA & 7);
  const int g1 = t + 256;
  const int rB = g1 >> 3, slotB = (g1 & 7) ^ (rB & 7);

  // prologue: tile 0 -> regs -> buf0
  float4 kr0, kr1, vr0, vr1;
  {
    const float4* kg = (const float4*)(k + (size_t)j0 * 32);
    const float4* vg = (const float4*)(v + (size_t)j0 * 32);
    kr0 = kg[t]; kr1 = kg[t + 256];
    vr0 = vg[t]; vr1 = vg[t + 256];
  }
  tiles[rA * 8 + slotA] = kr0;
  tiles[rB * 8 + slotB] = kr1;
  tiles[512 + rA * 8 + slotA] = vr0;
  tiles[512 + rB * 8 + slotB] = vr1;
  __syncthreads();

  const int h2 = head * 2;
  const int s0 = h2 ^ jg, s1 = (h2 + 1) ^ jg;
  int p = 0;
  for (int tt = 0; tt < 8; ++tt) {
    // issue next tile's global loads early; latency hides under this tile's compute
    if (tt + 1 < 8) {
      const float4* kg = (const float4*)(k + (size_t)(j0 + (tt + 1) * 64) * 32);
      const float4* vg = (const float4*)(v + (size_t)(j0 + (tt + 1) * 64) * 32);
      kr0 = kg[t]; kr1 = kg[t + 256];
      vr0 = vg[t]; vr1 = vg[t + 256];
    }
    const float4* kls = tiles + (p << 10);
    const float4* vls = kls + 512;
    // software-pipelined compute: fetch it+1's reads before it's u-loop
    float4 ka = kls[jg * 8 + s0];
    float4 kb = kls[jg * 8 + s1];
    float4 va = vls[jg * 8 + s0];
    float4 vb = vls[jg * 8 + s1];
#pragma unroll 2
    for (int it = 0; it < 8; ++it) {
      float4 ka2, kb2, va2, vb2;
      if (it < 7) {
        const int jn = (it + 1) * 8 + jg;
        ka2 = kls[jn * 8 + s0];
        kb2 = kls[jn * 8 + s1];
        va2 = vls[jn * 8 + s0];
        vb2 = vls[jn * 8 + s1];
      }
#pragma unroll
      for (int u = 0; u < 8; ++u) {
        float s = fmaf(qa[u].x, ka.x, mneg[u]);
        s = fmaf(qa[u].y, ka.y, s);
        s = fmaf(qa[u].z, ka.z, s);
        s = fmaf(qa[u].w, ka.w, s);
        s = fmaf(qb[u].x, kb.x, s);
        s = fmaf(qb[u].y, kb.y, s);
        s = fmaf(qb[u].z, kb.z, s);
        s = fmaf(qb[u].w, kb.w, s);
        const float p2 = __builtin_amdgcn_exp2f(s);
        l[u] += p2;
        accA[u].x = fmaf(p2, va.x, accA[u].x);
        accA[u].y = fmaf(p2, va.y, accA[u].y);
        accA[u].z = fmaf(p2, va.z, accA[u].z);
        accA[u].w = fmaf(p2, va.w, accA[u].w);
        accB[u].x = fmaf(p2, vb.x, accB[u].x);
        accB[u].y = fmaf(p2, vb.y, accB[u].y);
        accB[u].z = fmaf(p2, vb.z, accB[u].z);
        accB[u].w = fmaf(p2, vb.w, accB[u].w);
      }
      if (it < 7) { ka = ka2; kb = kb2; va = va2; vb = vb2; }
    }
    // write next tile into the other buffer; one barrier publishes it and
    // protects the just-read buffer from overwrite in the following iteration
    if (tt + 1 < 8) {
      float4* klsn = tiles + ((p ^ 1) << 10);
      float4* vlsn = klsn + 512;
      klsn[rA * 8 + slotA] = kr0;
      klsn[rB * 8 + slotB] = kr1;
      vlsn[rA * 8 + slotA] = vr0;
      vlsn[rB * 8 + slotB] = vr1;
      __syncthreads();
      p ^= 1;
    }
  }
  // butterfly-reduce the 8 jg partials (jg = lane bits 0..2); all lanes end with the sum
#pragma unroll
  for (int u = 0; u < 8; ++u) {
#pragma unroll
    for (int m = 1; m <= 4; m <<= 1) {
      accA[u].x += __shfl_xor(accA[u].x, m);
      accA[u].y += __shfl_xor(accA[u].y, m);
      accA[u].z += __shfl_xor(accA[u].z, m);
      accA[u].w += __shfl_xor(accA[u].w, m);
      accB[u].x += __shfl_xor(accB[u].x, m);
      accB[u].y += __shfl_xor(accB[u].y, m);
      accB[u].z += __shfl_xor(accB[u].z, m);
      accB[u].w += __shfl_xor(accB[u].w, m);
      l[u] += __shfl_xor(l[u], m);
    }
  }
  if (jg == 0) {
#pragma unroll
    for (int u = 0; u < 8; ++u) {
      const int row = r0 + rg * 8 + u;
      float* ap = apacc + (size_t)blockIdx.y * N * 32 + (size_t)row * 32 + head * 8;
      ((float4*)ap)[0] = accA[u];
      ((float4*)ap)[1] = accB[u];
      apl[(size_t)blockIdx.y * N * 4 + (size_t)row * 4 + head] = l[u];
    }
  }
}

// ---------------- combine attention partials ----------------
__global__ __launch_bounds__(256) void acombine(const float* __restrict__ apacc,
                                                const float* __restrict__ apl,
                                                float* __restrict__ attno) {
  const int e = blockIdx.x * 256 + threadIdx.x;  // < N*32
  const int row = e >> 5;
  const int hh = (e >> 3) & 3;
  float L = 0.f, S = 0.f;
#pragma unroll
  for (int jc = 0; jc < JC; ++jc) {
    L += apl[(size_t)jc * N * 4 + row * 4 + hh];
    S += apacc[(size_t)jc * N * 32 + e];
  }
  attno[e] = S / L;
}

// ---------------- O-projection + residual + LayerNorm1 ----------------
__global__ __launch_bounds__(256) void oln1_kernel(const float* __restrict__ attno,
                                                   const float* __restrict__ wo,
                                                   const float* __restrict__ bo,
                                                   const float* __restrict__ g,
                                                   const float* __restrict__ b,
                                                   float* __restrict__ h) {
  __shared__ float als[32][32];
  __shared__ float wols[32][32];
  __shared__ float ys[32][33];
  const int t = threadIdx.x;
  const int r0 = blockIdx.x * 32;
  ((float4*)&als[0][0])[t] = ((const float4*)(attno + (size_t)r0 * 32))[t];
  ((float4*)&wols[0][0])[t] = ((const float4*)wo)[t];
  __syncthreads();
  const int j = t & 31, og = t >> 5;
  float acc[4];
#pragma unroll
  for (int u = 0; u < 4; ++u) acc[u] = bo[j];
  for (int kk = 0; kk < 32; ++kk) {
    const float w = wols[kk][j];
#pragma unroll
    for (int u = 0; u < 4; ++u) acc[u] = fmaf(als[og * 4 + u][kk], w, acc[u]);
  }
#pragma unroll
  for (int u = 0; u < 4; ++u) {
    const int r = og * 4 + u;
    ys[r][j] = h[(size_t)(r0 + r) * 32 + j] + acc[u];
  }
  __syncthreads();
  if (t < 32) {
    float mu = 0.f;
#pragma unroll
    for (int c = 0; c < 32; ++c) mu += ys[t][c];
    mu *= (1.f / 32.f);
    float var = 0.f;
#pragma unroll
    for (int c = 0; c < 32; ++c) {
      const float dd = ys[t][c] - mu;
      var = fmaf(dd, dd, var);
    }
    var *= (1.f / 32.f);
    const float rs = rsqrtf(var + 1e-5f);
#pragma unroll
    for (int c = 0; c < 32; ++c)
      h[(size_t)(r0 + t) * 32 + c] = (ys[t][c] - mu) * rs * g[c] + b[c];
  }
}

// ---------------- FFN + residual + LayerNorm2 ----------------
__global__ __launch_bounds__(256) void ffn_kernel(const float* __restrict__ hin,
                                                  const float* __restrict__ w1,
                                                  const float* __restrict__ b1,
                                                  const float* __restrict__ w2,
                                                  const float* __restrict__ b2,
                                                  const float* __restrict__ g,
                                                  const float* __restrict__ bb,
                                                  float* __restrict__ h) {
  __shared__ float hs[32][32];
  __shared__ float w1s[32][64];
  __shared__ float w2s[64][32];
  __shared__ float mids[32][64];
  __shared__ float ys[32][33];
  const int t = threadIdx.x;
  const int r0 = blockIdx.x * 32;
  ((float4*)&hs[0][0])[t] = ((const float4*)(hin + (size_t)r0 * 32))[t];
#pragma unroll
  for (int i = 0; i < 2; ++i) {
    ((float4*)&w1s[0][0])[t + i * 256] = ((const float4*)w1)[t + i * 256];
    ((float4*)&w2s[0][0])[t + i * 256] = ((const float4*)w2)[t + i * 256];
  }
  __syncthreads();
  {
    const int jm = t & 63, gg = t >> 6;
    float acc[8];
#pragma unroll
    for (int u = 0; u < 8; ++u) acc[u] = b1[jm];
    for (int kk = 0; kk < 32; ++kk) {
      const float w = w1s[kk][jm];
#pragma unroll
      for (int u = 0; u < 8; ++u) acc[u] = fmaf(hs[gg * 8 + u][kk], w, acc[u]);
    }
#pragma unroll
    for (int u = 0; u < 8; ++u) mids[gg * 8 + u][jm] = fmaxf(acc[u], 0.f);
  }
  __syncthreads();
  {
    const int j = t & 31, og = t >> 5;
    float acc[4];
#pragma unroll
    for (int u = 0; u < 4; ++u) acc[u] = b2[j];
    for (int kk = 0; kk < 64; ++kk) {
      const float w = w2s[kk][j];
#pragma unroll
      for (int u = 0; u < 4; ++u) acc[u] = fmaf(mids[og * 4 + u][kk], w, acc[u]);
    }
#pragma unroll
    for (int u = 0; u < 4; ++u) {
      const int r = og * 4 + u;
      ys[r][j] = hs[r][j] + acc[u];
    }
  }
  __syncthreads();
  if (t < 32) {
    float mu = 0.f;
#pragma unroll
    for (int c = 0; c < 32; ++c) mu += ys[t][c];
    mu *= (1.f / 32.f);
    float var = 0.f;
#pragma unroll
    for (int c = 0; c < 32; ++c) {
      const float dd = ys[t][c] - mu;
      var = fmaf(dd, dd, var);
    }
    var *= (1.f / 32.f);
    const float rs = rsqrtf(var + 1e-5f);
#pragma unroll
    for (int c = 0; c < 32; ++c)
      h[(size_t)(r0 + t) * 32 + c] = (ys[t][c] - mu) * rs * g[c] + bb[c];
  }
}

// ---------------- head ----------------
__global__ __launch_bounds__(256) void headp_kernel(const float* __restrict__ h,
                                                    float* __restrict__ partial) {
  __shared__ float red[8][32];
  const int t = threadIdx.x;
  const int c = t & 31, rg = t >> 5;
  const int r0 = blockIdx.x * 64;
  float s = 0.f;
#pragma unroll
  for (int u = 0; u < 8; ++u) s += h[(size_t)(r0 + rg * 8 + u) * 32 + c];
  red[rg][c] = s;
  __syncthreads();
  if (t < 32) {
    float ss = 0.f;
#pragma unroll
    for (int u = 0; u < 8; ++u) ss += red[u][t];
    partial[blockIdx.x * 32 + t] = ss;
  }
}

__global__ __launch_bounds__(64) void headf_kernel(const float* __restrict__ partial,
                                                   const float* __restrict__ w1,
                                                   const float* __restrict__ b1,
                                                   const float* __restrict__ w2,
                                                   const float* __restrict__ b2,
                                                   float* __restrict__ out) {
  __shared__ float mls[32];
  __shared__ float tls[16];
  const int t = threadIdx.x;
  if (t < 32) {
    float s = 0.f;
    for (int bb = 0; bb < 64; ++bb) s += partial[bb * 32 + t];
    mls[t] = s * (1.f / 4096.f);
  }
  __syncthreads();
  if (t < 16) {
    float a = b1[t];
#pragma unroll
    for (int c = 0; c < 32; ++c) a = fmaf(mls[c], w1[c * 16 + t], a);
    tls[t] = tanhf(a);
  }
  __syncthreads();
  if (t == 0) {
    float o = b2[0];
#pragma unroll
    for (int jj = 0; jj < 16; ++jj) o = fmaf(tls[jj], w2[jj], o);
    out[0] = o;
  }
}

extern "C" void kernel_launch(void* const* d_in, const int* in_sizes, int n_in,
                              void* d_out, int out_size, void* d_ws, size_t ws_size,
                              hipStream_t stream) {
  const float* x      = (const float*)d_in[0];
  const float* enc_w1 = (const float*)d_in[1];
  const float* enc_b1 = (const float*)d_in[2];
  const float* enc_w2 = (const float*)d_in[3];
  const float* enc_b2 = (const float*)d_in[4];
  const float* enc_w3 = (const float*)d_in[5];
  const float* enc_b3 = (const float*)d_in[6];
  const float* wq     = (const float*)d_in[7];
  const float* bq     = (const float*)d_in[8];
  const float* wk     = (const float*)d_in[9];
  const float* bk     = (const float*)d_in[10];
  const float* wv     = (const float*)d_in[11];
  const float* bv     = (const float*)d_in[12];
  const float* wo     = (const float*)d_in[13];
  const float* bo     = (const float*)d_in[14];
  const float* ln1_g  = (const float*)d_in[15];
  const float* ln1_b  = (const float*)d_in[16];
  const float* ffn_w1 = (const float*)d_in[17];
  const float* ffn_b1 = (const float*)d_in[18];
  const float* ffn_w2 = (const float*)d_in[19];
  const float* ffn_b2 = (const float*)d_in[20];
  const float* ln2_g  = (const float*)d_in[21];
  const float* ln2_b  = (const float*)d_in[22];
  const float* head_w1 = (const float*)d_in[23];
  const float* head_b1 = (const float*)d_in[24];
  const float* head_w2 = (const float*)d_in[25];
  const float* head_b2 = (const float*)d_in[26];

  float* ws      = (float*)d_ws;
  float* latent  = ws;                    // 131072
  float* normed  = ws + 131072;           // 131072
  float* h       = ws + 262144;           // 131072
  float* q       = ws + 393216;           // 131072
  float* k       = ws + 524288;           // 131072
  float* v       = ws + 655360;           // 131072
  float* attno   = ws + 786432;           // 131072
  float* shreg   = ws + 917504;           // shared region: pool partials, then attn partials
  float* p_acc   = shreg;                 // pool: 8*131072
  float* p_deg   = shreg + 1048576;       // pool: 8*4096
  float* a_acc   = shreg;                 // attn: 8*131072
  float* a_l     = shreg + 1048576;       // attn: 8*16384
  int*   kmax2i  = (int*)(ws + 2097152);  // 8 ints (4 per transformer block)
  float* partial = ws + 2097216;          // 2048

  hipMemsetAsync(kmax2i, 0, 8 * sizeof(int), stream);

  enc_kernel<<<512, 256, 0, stream>>>(x, enc_w1, enc_b1, enc_w2, enc_b2, enc_w3, enc_b3,
                                      latent, normed);
  pool_kernel<<<dim3(64, JC), 256, 0, stream>>>(normed, latent, p_acc, p_deg);
  pool_combine<<<512, 256, 0, stream>>>(latent, p_acc, p_deg, h);

  for (int blk = 0; blk < 2; ++blk) {
    qkv_kernel<<<128, 256, 0, stream>>>(h, wq + blk * 1024, bq + blk * 32,
                                        wk + blk * 1024, bk + blk * 32,
                                        wv + blk * 1024, bv + blk * 32, q, k, v,
                                        kmax2i + blk * 4);
    attn_kernel<<<dim3(64, JC), 256, 0, stream>>>(q, k, v, kmax2i + blk * 4, a_acc, a_l);
    acombine<<<512, 256, 0, stream>>>(a_acc, a_l, attno);
    oln1_kernel<<<128, 256, 0, stream>>>(attno, wo + blk * 1024, bo + blk * 32,
                                         ln1_g + blk * 32, ln1_b + blk * 32, h);
    ffn_kernel<<<128, 256, 0, stream>>>(h, ffn_w1 + blk * 2048, ffn_b1 + blk * 64,
                                        ffn_w2 + blk * 2048, ffn_b2 + blk * 32,
                                        ln2_g + blk * 32, ln2_b + blk * 32, h);
  }

  headp_kernel<<<64, 256, 0, stream>>>(h, partial);
  headf_kernel<<<1, 64, 0, stream>>>(partial, head_w1, head_b1, head_w2, head_b2, (float*)d_out);
}

// Round 8
// 170.796 us; speedup vs baseline: 1.1061x; 1.1061x over previous
//
#include <hip/hip_runtime.h>
#include <math.h>

#define N 4096
#define DIN 512
#define D 32
#define JC 8

typedef float v2f __attribute__((ext_vector_type(2)));
__device__ __forceinline__ v2f fma2(v2f a, float b, v2f c) {
  v2f bb; bb.x = b; bb.y = b;
  return __builtin_elementwise_fma(a, bb, c);
}

// ---------------- encoder: x[4096,512] -> latent[4096,32] + normed rows, fused ----------------
// R6: k-split layer 1 (w1 read once per block; partials reduced via LDS). Left top-5.
__global__ __launch_bounds__(256) void enc_kernel(
    const float* __restrict__ x,
    const float* __restrict__ w1, const float* __restrict__ b1,
    const float* __restrict__ w2, const float* __restrict__ b2,
    const float* __restrict__ w3, const float* __restrict__ b3,
    float* __restrict__ latent, float* __restrict__ normed) {
  __shared__ float xs[8][512];       // 16 KB
  __shared__ float h1p[4][8][128];   // 16 KB layer-1 partials (per k-quarter)
  __shared__ float h1s[8][128];      // 4 KB
  __shared__ float h2s[8][64];       // 2 KB
  __shared__ float w2s[128][64];     // 32 KB
  __shared__ float w3s[64][32];      // 8 KB   -> total 78 KB = 2 blocks/CU
  const int t = threadIdx.x;
  const int r0 = blockIdx.x * 8;

  // stage x rows + w2 + w3 into LDS (one barrier covers all)
  const float4* xg = (const float4*)(x + (size_t)r0 * DIN);
  float4* xl = (float4*)&xs[0][0];
#pragma unroll
  for (int i = 0; i < 4; ++i) xl[t + i * 256] = xg[t + i * 256];
  float4* w2l = (float4*)&w2s[0][0];
  const float4* w2g = (const float4*)w2;
#pragma unroll
  for (int i = 0; i < 8; ++i) w2l[t + i * 256] = w2g[t + i * 256];
  float4* w3l = (float4*)&w3s[0][0];
  const float4* w3g = (const float4*)w3;
#pragma unroll
  for (int i = 0; i < 2; ++i) w3l[t + i * 256] = w3g[t + i * 256];
  __syncthreads();

  // layer 1: 512 -> 128. wave kq handles its k-quarter for all 8 rows x 2 cols.
  {
    const int jc2 = (t & 63) * 2;
    const int kq = t >> 6;
    const int kb = kq * 128;
    float a0[8], a1[8];
#pragma unroll
    for (int r = 0; r < 8; ++r) { a0[r] = 0.f; a1[r] = 0.f; }
    const float* wp = w1 + (size_t)kb * 128 + jc2;

#define ENC_LD4(P0, P1, P2, P3, KK)                          \
    P0 = *(const float2*)&wp[(size_t)(KK) * 128];            \
    P1 = *(const float2*)&wp[(size_t)((KK) + 1) * 128];      \
    P2 = *(const float2*)&wp[(size_t)((KK) + 2) * 128];      \
    P3 = *(const float2*)&wp[(size_t)((KK) + 3) * 128];

#define ENC_STEP(W0, WA, WB, WC, KK)                                   \
    {                                                                  \
      _Pragma("unroll")                                                \
      for (int r = 0; r < 8; ++r) {                                    \
        const float4 xv = *(const float4*)&xs[r][kb + (KK)];           \
        a0[r] = fmaf(xv.x, W0.x, a0[r]); a1[r] = fmaf(xv.x, W0.y, a1[r]); \
        a0[r] = fmaf(xv.y, WA.x, a0[r]); a1[r] = fmaf(xv.y, WA.y, a1[r]); \
        a0[r] = fmaf(xv.z, WB.x, a0[r]); a1[r] = fmaf(xv.z, WB.y, a1[r]); \
        a0[r] = fmaf(xv.w, WC.x, a0[r]); a1[r] = fmaf(xv.w, WC.y, a1[r]); \
      }                                                                \
    }

    float2 A0, A1, A2, A3, B0, B1, B2, B3, C0, C1, C2, C3, D0, D1, D2, D3;
    ENC_LD4(A0, A1, A2, A3, 0)
    ENC_LD4(B0, B1, B2, B3, 4)
    ENC_LD4(C0, C1, C2, C3, 8)
    ENC_LD4(D0, D1, D2, D3, 12)
    for (int kk = 0; kk < 128; kk += 16) {
      ENC_STEP(A0, A1, A2, A3, kk + 0);
      if (kk + 16 < 128) { ENC_LD4(A0, A1, A2, A3, kk + 16) }
      ENC_STEP(B0, B1, B2, B3, kk + 4);
      if (kk + 20 < 128) { ENC_LD4(B0, B1, B2, B3, kk + 20) }
      ENC_STEP(C0, C1, C2, C3, kk + 8);
      if (kk + 24 < 128) { ENC_LD4(C0, C1, C2, C3, kk + 24) }
      ENC_STEP(D0, D1, D2, D3, kk + 12);
      if (kk + 28 < 128) { ENC_LD4(D0, D1, D2, D3, kk + 28) }
    }
#undef ENC_STEP
#undef ENC_LD4
#pragma unroll
    for (int r = 0; r < 8; ++r) {
      h1p[kq][r][jc2] = a0[r];
      h1p[kq][r][jc2 + 1] = a1[r];
    }
  }
  __syncthreads();

  // reduce the 4 k-quarter partials + bias + relu (1024 outputs)
#pragma unroll
  for (int e0 = 0; e0 < 1024; e0 += 256) {
    const int e = e0 + t;
    const int r = e >> 7, c = e & 127;
    const float s = b1[c] + ((h1p[0][r][c] + h1p[1][r][c]) + (h1p[2][r][c] + h1p[3][r][c]));
    h1s[r][c] = fmaxf(s, 0.f);
  }
  __syncthreads();

  // layer 2: 128 -> 64, relu. weights from LDS (w2s), h1 broadcast reads
  {
    const int j = t & 63, rg = t >> 6;
    const int ra = rg * 2, rb = ra + 1;
    float a0 = b2[j], a1 = b2[j];
#pragma unroll 8
    for (int kk = 0; kk < 128; ++kk) {
      const float w = w2s[kk][j];
      a0 = fmaf(h1s[ra][kk], w, a0);
      a1 = fmaf(h1s[rb][kk], w, a1);
    }
    h2s[ra][j] = fmaxf(a0, 0.f);
    h2s[rb][j] = fmaxf(a1, 0.f);
  }
  __syncthreads();

  // layer 3: 64 -> 32 + fused row-normalize (shfl reduce over the 32 j-lanes)
  {
    const int j = t & 31, og = t >> 5;  // 8 rows, 1 per group
    float acc = b3[j];
#pragma unroll 8
    for (int kk = 0; kk < 64; ++kk) acc = fmaf(h2s[og][kk], w3s[kk][j], acc);
    float s2 = acc * acc;
    s2 += __shfl_xor(s2, 1);
    s2 += __shfl_xor(s2, 2);
    s2 += __shfl_xor(s2, 4);
    s2 += __shfl_xor(s2, 8);
    s2 += __shfl_xor(s2, 16);
    const float inv = 1.0f / (sqrtf(s2) + 1e-12f);
    const size_t off = (size_t)(r0 + og) * D + j;
    latent[off] = acc;
    normed[off] = acc * inv;
  }
}

// ---------------- graph pool partials: block (bi, bj) covers 64 i-rows x 512 j ----------------
__global__ __launch_bounds__(256) void pool_kernel(const float* __restrict__ normed,
                                                   const float* __restrict__ latent,
                                                   float* __restrict__ pacc,
                                                   float* __restrict__ pdeg) {
  __shared__ float smem[8192 + 256];
  float* nt = smem;
  float* lt = smem + 4096;
  float* degr = smem + 8192;
  const int t = threadIdx.x;
  const int il = t & 63, g = t >> 6;
  const int i0 = blockIdx.x * 64;
  const int j0 = blockIdx.y * 512;

  float ni[32];
  const float* nrow = normed + (size_t)(i0 + il) * D;
#pragma unroll
  for (int c = 0; c < 32; ++c) ni[c] = nrow[c];

  float acc[32];
#pragma unroll
  for (int c = 0; c < 32; ++c) acc[c] = 0.f;
  float deg = 0.f;

  for (int jt = j0; jt < j0 + 512; jt += 128) {
    __syncthreads();
    const float4* ng = (const float4*)(normed + (size_t)jt * D);
    const float4* lg = (const float4*)(latent + (size_t)jt * D);
    float4* ntl = (float4*)nt;
    float4* ltl = (float4*)lt;
#pragma unroll
    for (int i = 0; i < 4; ++i) {
      ntl[t + i * 256] = ng[t + i * 256];
      ltl[t + i * 256] = lg[t + i * 256];
    }
    __syncthreads();
    for (int jj = g; jj < 128; jj += 4) {
      const float* nr = nt + jj * 32;
      float s = 0.f;
#pragma unroll
      for (int c = 0; c < 32; ++c) s = fmaf(ni[c], nr[c], s);
      if (s >= 0.9f) {
        deg += 1.f;
        const float* lrow = lt + jj * 32;
#pragma unroll
        for (int c = 0; c < 32; ++c) acc[c] += lrow[c];
      }
    }
  }
  __syncthreads();
  float* accr = smem;
#pragma unroll
  for (int c = 0; c < 32; ++c) accr[(g * 64 + il) * 32 + c] = acc[c];
  degr[t] = deg;
  __syncthreads();
  for (int e = t; e < 64 * 32; e += 256) {
    const float s = accr[e] + accr[2048 + e] + accr[4096 + e] + accr[6144 + e];
    pacc[((size_t)blockIdx.y * N + i0 + (e >> 5)) * 32 + (e & 31)] = s;
  }
  if (t < 64) {
    pdeg[(size_t)blockIdx.y * N + i0 + t] = degr[t] + degr[64 + t] + degr[128 + t] + degr[192 + t];
  }
}

// ---------------- combine pool partials -> h = latent + (mask@latent)/deg ----------------
__global__ __launch_bounds__(256) void pool_combine(const float* __restrict__ latent,
                                                    const float* __restrict__ pacc,
                                                    const float* __restrict__ pdeg,
                                                    float* __restrict__ h) {
  const int e = blockIdx.x * 256 + threadIdx.x;
  const int i = e >> 5;
  float s = 0.f, dg = 0.f;
#pragma unroll
  for (int gch = 0; gch < JC; ++gch) {
    s += pacc[(size_t)gch * N * 32 + e];
    dg += pdeg[(size_t)gch * N + i];
  }
  h[e] = latent[e] + s / dg;
}

// ---------------- fused QKV projection (q pre-scaled by log2e/sqrt(8)) + k-norm max ----------------
__global__ __launch_bounds__(256) void qkv_kernel(
    const float* __restrict__ h,
    const float* __restrict__ wq, const float* __restrict__ bq,
    const float* __restrict__ wk, const float* __restrict__ bk,
    const float* __restrict__ wv, const float* __restrict__ bv,
    float* __restrict__ q, float* __restrict__ k, float* __restrict__ v,
    int* __restrict__ kmax2i) {
  __shared__ float hs[32][32];
  __shared__ float wsm[3][32][32];
  __shared__ int kred[4];
  const int t = threadIdx.x;
  const int r0 = blockIdx.x * 32;
  if (t < 4) kred[t] = 0;
  ((float4*)&hs[0][0])[t] = ((const float4*)(h + (size_t)r0 * 32))[t];
  ((float4*)&wsm[0][0][0])[t] = ((const float4*)wq)[t];
  ((float4*)&wsm[1][0][0])[t] = ((const float4*)wk)[t];
  ((float4*)&wsm[2][0][0])[t] = ((const float4*)wv)[t];
  __syncthreads();
  const int j = t & 31, og = t >> 5;
  const int head = j >> 3;
  float aq[4], ak[4], av[4];
#pragma unroll
  for (int u = 0; u < 4; ++u) { aq[u] = bq[j]; ak[u] = bk[j]; av[u] = bv[j]; }
  for (int kk = 0; kk < 32; ++kk) {
    const float wqv = wsm[0][kk][j], wkv = wsm[1][kk][j], wvv = wsm[2][kk][j];
#pragma unroll
    for (int u = 0; u < 4; ++u) {
      const float hh = hs[og * 4 + u][kk];
      aq[u] = fmaf(hh, wqv, aq[u]);
      ak[u] = fmaf(hh, wkv, ak[u]);
      av[u] = fmaf(hh, wvv, av[u]);
    }
  }
  const float scale = 1.4426950408889634f * 0.35355339059327373f;  // log2(e)/sqrt(8)
#pragma unroll
  for (int u = 0; u < 4; ++u) {
    const size_t off = (size_t)(r0 + og * 4 + u) * 32 + j;
    q[off] = aq[u] * scale;
    k[off] = ak[u];
    v[off] = av[u];
  }
  // per-(row,head) ||k8||^2 via shfl over the 8 lanes of this head; block-max; global atomicMax
#pragma unroll
  for (int u = 0; u < 4; ++u) {
    float s2 = ak[u] * ak[u];
    s2 += __shfl_xor(s2, 1);
    s2 += __shfl_xor(s2, 2);
    s2 += __shfl_xor(s2, 4);
    if ((j & 7) == 0) atomicMax(&kred[head], __float_as_int(s2));
  }
  __syncthreads();
  if (t < 4) atomicMax(&kmax2i[t], kred[t]);
}

// ---------------- attention partials: block (rowBlk, jChunk); 64 rows x 512 j ----------------
// R8: staging reverted to the R6 structure (single buffer + reg prefetch, 49.2 us; R7's
// dbuf regressed to 54.3 -- the it<7 guards + reg rotation + runtime LDS base cost more
// than the barrier it saved). New: PACKED FP32 inner loop. q-rows are processed in pairs
// (u=2pr, 2pr+1) living in the lo/hi halves of v2f registers; every score/pv fma becomes
// one v_pk_fma_f32 serving both rows (ka.x broadcast via op_sel), l becomes v_pk_add.
// 19 instrs per 2 rows vs 36 scalar -> ~1.7x fewer VALU issues (the measured 26 us busy
// floor). Per-row FP chain order is IDENTICAL to the scalar version -> bit-identical.
__global__ __launch_bounds__(256) __attribute__((amdgpu_waves_per_eu(2, 2)))
void attn_kernel(const float* __restrict__ q,
                 const float* __restrict__ k,
                 const float* __restrict__ v,
                 const int* __restrict__ kmax2i,
                 float* __restrict__ apacc,
                 float* __restrict__ apl) {
  __shared__ float4 tiles[1024];  // kls[64*8] | vls[64*8], chunk-XOR swizzled
  float4* kls = tiles;
  float4* vls = tiles + 512;
  const int t = threadIdx.x;
  const int jg = t & 7, head = (t >> 3) & 3, rg = t >> 5;
  const int r0 = blockIdx.x * 64;
  const int j0 = blockIdx.y * (N / JC);

  const float km2 = __int_as_float(kmax2i[head]);

  // q-row pairs: component c of rows (2pr, 2pr+1) in lo/hi of qq[pr][c]
  v2f qq[4][8], acc[4][8], mneg2[4], l2[4];
#pragma unroll
  for (int pr = 0; pr < 4; ++pr) {
    const float* qr0 = q + (size_t)(r0 + rg * 8 + 2 * pr) * 32 + head * 8;
    const float* qr1 = qr0 + 32;
    const float4 qa0 = ((const float4*)qr0)[0], qb0 = ((const float4*)qr0)[1];
    const float4 qa1 = ((const float4*)qr1)[0], qb1 = ((const float4*)qr1)[1];
    qq[pr][0].x = qa0.x; qq[pr][0].y = qa1.x;
    qq[pr][1].x = qa0.y; qq[pr][1].y = qa1.y;
    qq[pr][2].x = qa0.z; qq[pr][2].y = qa1.z;
    qq[pr][3].x = qa0.w; qq[pr][3].y = qa1.w;
    qq[pr][4].x = qb0.x; qq[pr][4].y = qb1.x;
    qq[pr][5].x = qb0.y; qq[pr][5].y = qb1.y;
    qq[pr][6].x = qb0.z; qq[pr][6].y = qb1.z;
    qq[pr][7].x = qb0.w; qq[pr][7].y = qb1.w;
    const float qn0 = qa0.x * qa0.x + qa0.y * qa0.y + qa0.z * qa0.z + qa0.w * qa0.w +
                      qb0.x * qb0.x + qb0.y * qb0.y + qb0.z * qb0.z + qb0.w * qb0.w;
    const float qn1 = qa1.x * qa1.x + qa1.y * qa1.y + qa1.z * qa1.z + qa1.w * qa1.w +
                      qb1.x * qb1.x + qb1.y * qb1.y + qb1.z * qb1.z + qb1.w * qb1.w;
    mneg2[pr].x = -sqrtf(qn0 * km2);
    mneg2[pr].y = -sqrtf(qn1 * km2);
    l2[pr].x = 0.f; l2[pr].y = 0.f;
#pragma unroll
    for (int c = 0; c < 8; ++c) { acc[pr][c].x = 0.f; acc[pr][c].y = 0.f; }
  }

  // prologue: load tile 0 into registers
  float4 kr0, kr1, vr0, vr1;
  {
    const float4* kg = (const float4*)(k + (size_t)j0 * 32);
    const float4* vg = (const float4*)(v + (size_t)j0 * 32);
    kr0 = kg[t]; kr1 = kg[t + 256];
    vr0 = vg[t]; vr1 = vg[t + 256];
  }

  // precomputed swizzle slots for the two staged quarters
  const int rA = t >> 3, slotA = (t & 7) ^ (rA & 7);
  const int g1 = t + 256;
  const int rB = g1 >> 3, slotB = (g1 & 7) ^ (rB & 7);

  const int h2 = head * 2;
  const int s0 = h2 ^ jg, s1 = (h2 + 1) ^ jg;
  for (int jt = j0; jt < j0 + (N / JC); jt += 64) {
    __syncthreads();
    kls[rA * 8 + slotA] = kr0;
    kls[rB * 8 + slotB] = kr1;
    vls[rA * 8 + slotA] = vr0;
    vls[rB * 8 + slotB] = vr1;
    __syncthreads();
    if (jt + 64 < j0 + (N / JC)) {
      const float4* kg = (const float4*)(k + (size_t)(jt + 64) * 32);
      const float4* vg = (const float4*)(v + (size_t)(jt + 64) * 32);
      kr0 = kg[t]; kr1 = kg[t + 256];
      vr0 = vg[t]; vr1 = vg[t + 256];
    }
#pragma unroll 2
    for (int it = 0; it < 8; ++it) {
      const int jj = it * 8 + jg;
      const float4 ka = kls[jj * 8 + s0];
      const float4 kb = kls[jj * 8 + s1];
      const float4 va = vls[jj * 8 + s0];
      const float4 vb = vls[jj * 8 + s1];
#pragma unroll
      for (int pr = 0; pr < 4; ++pr) {
        v2f s2 = mneg2[pr];
        s2 = fma2(qq[pr][0], ka.x, s2);
        s2 = fma2(qq[pr][1], ka.y, s2);
        s2 = fma2(qq[pr][2], ka.z, s2);
        s2 = fma2(qq[pr][3], ka.w, s2);
        s2 = fma2(qq[pr][4], kb.x, s2);
        s2 = fma2(qq[pr][5], kb.y, s2);
        s2 = fma2(qq[pr][6], kb.z, s2);
        s2 = fma2(qq[pr][7], kb.w, s2);
        v2f p2;
        p2.x = __builtin_amdgcn_exp2f(s2.x);
        p2.y = __builtin_amdgcn_exp2f(s2.y);
        l2[pr] += p2;
        acc[pr][0] = fma2(p2, va.x, acc[pr][0]);
        acc[pr][1] = fma2(p2, va.y, acc[pr][1]);
        acc[pr][2] = fma2(p2, va.z, acc[pr][2]);
        acc[pr][3] = fma2(p2, va.w, acc[pr][3]);
        acc[pr][4] = fma2(p2, vb.x, acc[pr][4]);
        acc[pr][5] = fma2(p2, vb.y, acc[pr][5]);
        acc[pr][6] = fma2(p2, vb.z, acc[pr][6]);
        acc[pr][7] = fma2(p2, vb.w, acc[pr][7]);
      }
    }
  }
  // butterfly-reduce the 8 jg partials (jg = lane bits 0..2); all lanes end with the sum
#pragma unroll
  for (int pr = 0; pr < 4; ++pr) {
#pragma unroll
    for (int m = 1; m <= 4; m <<= 1) {
#pragma unroll
      for (int c = 0; c < 8; ++c) {
        acc[pr][c].x += __shfl_xor(acc[pr][c].x, m);
        acc[pr][c].y += __shfl_xor(acc[pr][c].y, m);
      }
      l2[pr].x += __shfl_xor(l2[pr].x, m);
      l2[pr].y += __shfl_xor(l2[pr].y, m);
    }
  }
  if (jg == 0) {
    const size_t abase = (size_t)blockIdx.y * N * 32;
    const size_t lbase = (size_t)blockIdx.y * N * 4;
#pragma unroll
    for (int pr = 0; pr < 4; ++pr) {
      const int row0 = r0 + rg * 8 + 2 * pr;
      float* ap0 = apacc + abase + (size_t)row0 * 32 + head * 8;
      float* ap1 = ap0 + 32;
#pragma unroll
      for (int c = 0; c < 8; ++c) {
        ap0[c] = acc[pr][c].x;
        ap1[c] = acc[pr][c].y;
      }
      apl[lbase + (size_t)row0 * 4 + head] = l2[pr].x;
      apl[lbase + (size_t)(row0 + 1) * 4 + head] = l2[pr].y;
    }
  }
}

// ---------------- combine attention partials ----------------
__global__ __launch_bounds__(256) void acombine(const float* __restrict__ apacc,
                                                const float* __restrict__ apl,
                                                float* __restrict__ attno) {
  const int e = blockIdx.x * 256 + threadIdx.x;  // < N*32
  const int row = e >> 5;
  const int hh = (e >> 3) & 3;
  float L = 0.f, S = 0.f;
#pragma unroll
  for (int jc = 0; jc < JC; ++jc) {
    L += apl[(size_t)jc * N * 4 + row * 4 + hh];
    S += apacc[(size_t)jc * N * 32 + e];
  }
  attno[e] = S / L;
}

// ---------------- O-projection + residual + LayerNorm1 ----------------
__global__ __launch_bounds__(256) void oln1_kernel(const float* __restrict__ attno,
                                                   const float* __restrict__ wo,
                                                   const float* __restrict__ bo,
                                                   const float* __restrict__ g,
                                                   const float* __restrict__ b,
                                                   float* __restrict__ h) {
  __shared__ float als[32][32];
  __shared__ float wols[32][32];
  __shared__ float ys[32][33];
  const int t = threadIdx.x;
  const int r0 = blockIdx.x * 32;
  ((float4*)&als[0][0])[t] = ((const float4*)(attno + (size_t)r0 * 32))[t];
  ((float4*)&wols[0][0])[t] = ((const float4*)wo)[t];
  __syncthreads();
  const int j = t & 31, og = t >> 5;
  float acc[4];
#pragma unroll
  for (int u = 0; u < 4; ++u) acc[u] = bo[j];
  for (int kk = 0; kk < 32; ++kk) {
    const float w = wols[kk][j];
#pragma unroll
    for (int u = 0; u < 4; ++u) acc[u] = fmaf(als[og * 4 + u][kk], w, acc[u]);
  }
#pragma unroll
  for (int u = 0; u < 4; ++u) {
    const int r = og * 4 + u;
    ys[r][j] = h[(size_t)(r0 + r) * 32 + j] + acc[u];
  }
  __syncthreads();
  if (t < 32) {
    float mu = 0.f;
#pragma unroll
    for (int c = 0; c < 32; ++c) mu += ys[t][c];
    mu *= (1.f / 32.f);
    float var = 0.f;
#pragma unroll
    for (int c = 0; c < 32; ++c) {
      const float dd = ys[t][c] - mu;
      var = fmaf(dd, dd, var);
    }
    var *= (1.f / 32.f);
    const float rs = rsqrtf(var + 1e-5f);
#pragma unroll
    for (int c = 0; c < 32; ++c)
      h[(size_t)(r0 + t) * 32 + c] = (ys[t][c] - mu) * rs * g[c] + b[c];
  }
}

// ---------------- FFN + residual + LayerNorm2 ----------------
__global__ __launch_bounds__(256) void ffn_kernel(const float* __restrict__ hin,
                                                  const float* __restrict__ w1,
                                                  const float* __restrict__ b1,
                                                  const float* __restrict__ w2,
                                                  const float* __restrict__ b2,
                                                  const float* __restrict__ g,
                                                  const float* __restrict__ bb,
                                                  float* __restrict__ h) {
  __shared__ float hs[32][32];
  __shared__ float w1s[32][64];
  __shared__ float w2s[64][32];
  __shared__ float mids[32][64];
  __shared__ float ys[32][33];
  const int t = threadIdx.x;
  const int r0 = blockIdx.x * 32;
  ((float4*)&hs[0][0])[t] = ((const float4*)(hin + (size_t)r0 * 32))[t];
#pragma unroll
  for (int i = 0; i < 2; ++i) {
    ((float4*)&w1s[0][0])[t + i * 256] = ((const float4*)w1)[t + i * 256];
    ((float4*)&w2s[0][0])[t + i * 256] = ((const float4*)w2)[t + i * 256];
  }
  __syncthreads();
  {
    const int jm = t & 63, gg = t >> 6;
    float acc[8];
#pragma unroll
    for (int u = 0; u < 8; ++u) acc[u] = b1[jm];
    for (int kk = 0; kk < 32; ++kk) {
      const float w = w1s[kk][jm];
#pragma unroll
      for (int u = 0; u < 8; ++u) acc[u] = fmaf(hs[gg * 8 + u][kk], w, acc[u]);
    }
#pragma unroll
    for (int u = 0; u < 8; ++u) mids[gg * 8 + u][jm] = fmaxf(acc[u], 0.f);
  }
  __syncthreads();
  {
    const int j = t & 31, og = t >> 5;
    float acc[4];
#pragma unroll
    for (int u = 0; u < 4; ++u) acc[u] = b2[j];
    for (int kk = 0; kk < 64; ++kk) {
      const float w = w2s[kk][j];
#pragma unroll
      for (int u = 0; u < 4; ++u) acc[u] = fmaf(mids[og * 4 + u][kk], w, acc[u]);
    }
#pragma unroll
    for (int u = 0; u < 4; ++u) {
      const int r = og * 4 + u;
      ys[r][j] = hs[r][j] + acc[u];
    }
  }
  __syncthreads();
  if (t < 32) {
    float mu = 0.f;
#pragma unroll
    for (int c = 0; c < 32; ++c) mu += ys[t][c];
    mu *= (1.f / 32.f);
    float var = 0.f;
#pragma unroll
    for (int c = 0; c < 32; ++c) {
      const float dd = ys[t][c] - mu;
      var = fmaf(dd, dd, var);
    }
    var *= (1.f / 32.f);
    const float rs = rsqrtf(var + 1e-5f);
#pragma unroll
    for (int c = 0; c < 32; ++c)
      h[(size_t)(r0 + t) * 32 + c] = (ys[t][c] - mu) * rs * g[c] + bb[c];
  }
}

// ---------------- head ----------------
__global__ __launch_bounds__(256) void headp_kernel(const float* __restrict__ h,
                                                    float* __restrict__ partial) {
  __shared__ float red[8][32];
  const int t = threadIdx.x;
  const int c = t & 31, rg = t >> 5;
  const int r0 = blockIdx.x * 64;
  float s = 0.f;
#pragma unroll
  for (int u = 0; u < 8; ++u) s += h[(size_t)(r0 + rg * 8 + u) * 32 + c];
  red[rg][c] = s;
  __syncthreads();
  if (t < 32) {
    float ss = 0.f;
#pragma unroll
    for (int u = 0; u < 8; ++u) ss += red[u][t];
    partial[blockIdx.x * 32 + t] = ss;
  }
}

__global__ __launch_bounds__(64) void headf_kernel(const float* __restrict__ partial,
                                                   const float* __restrict__ w1,
                                                   const float* __restrict__ b1,
                                                   const float* __restrict__ w2,
                                                   const float* __restrict__ b2,
                                                   float* __restrict__ out) {
  __shared__ float mls[32];
  __shared__ float tls[16];
  const int t = threadIdx.x;
  if (t < 32) {
    float s = 0.f;
    for (int bb = 0; bb < 64; ++bb) s += partial[bb * 32 + t];
    mls[t] = s * (1.f / 4096.f);
  }
  __syncthreads();
  if (t < 16) {
    float a = b1[t];
#pragma unroll
    for (int c = 0; c < 32; ++c) a = fmaf(mls[c], w1[c * 16 + t], a);
    tls[t] = tanhf(a);
  }
  __syncthreads();
  if (t == 0) {
    float o = b2[0];
#pragma unroll
    for (int jj = 0; jj < 16; ++jj) o = fmaf(tls[jj], w2[jj], o);
    out[0] = o;
  }
}

extern "C" void kernel_launch(void* const* d_in, const int* in_sizes, int n_in,
                              void* d_out, int out_size, void* d_ws, size_t ws_size,
                              hipStream_t stream) {
  const float* x      = (const float*)d_in[0];
  const float* enc_w1 = (const float*)d_in[1];
  const float* enc_b1 = (const float*)d_in[2];
  const float* enc_w2 = (const float*)d_in[3];
  const float* enc_b2 = (const float*)d_in[4];
  const float* enc_w3 = (const float*)d_in[5];
  const float* enc_b3 = (const float*)d_in[6];
  const float* wq     = (const float*)d_in[7];
  const float* bq     = (const float*)d_in[8];
  const float* wk     = (const float*)d_in[9];
  const float* bk     = (const float*)d_in[10];
  const float* wv     = (const float*)d_in[11];
  const float* bv     = (const float*)d_in[12];
  const float* wo     = (const float*)d_in[13];
  const float* bo     = (const float*)d_in[14];
  const float* ln1_g  = (const float*)d_in[15];
  const float* ln1_b  = (const float*)d_in[16];
  const float* ffn_w1 = (const float*)d_in[17];
  const float* ffn_b1 = (const float*)d_in[18];
  const float* ffn_w2 = (const float*)d_in[19];
  const float* ffn_b2 = (const float*)d_in[20];
  const float* ln2_g  = (const float*)d_in[21];
  const float* ln2_b  = (const float*)d_in[22];
  const float* head_w1 = (const float*)d_in[23];
  const float* head_b1 = (const float*)d_in[24];
  const float* head_w2 = (const float*)d_in[25];
  const float* head_b2 = (const float*)d_in[26];

  float* ws      = (float*)d_ws;
  float* latent  = ws;                    // 131072
  float* normed  = ws + 131072;           // 131072
  float* h       = ws + 262144;           // 131072
  float* q       = ws + 393216;           // 131072
  float* k       = ws + 524288;           // 131072
  float* v       = ws + 655360;           // 131072
  float* attno   = ws + 786432;           // 131072
  float* shreg   = ws + 917504;           // shared region: pool partials, then attn partials
  float* p_acc   = shreg;                 // pool: 8*131072
  float* p_deg   = shreg + 1048576;       // pool: 8*4096
  float* a_acc   = shreg;                 // attn: 8*131072
  float* a_l     = shreg + 1048576;       // attn: 8*16384
  int*   kmax2i  = (int*)(ws + 2097152);  // 8 ints (4 per transformer block)
  float* partial = ws + 2097216;          // 2048

  hipMemsetAsync(kmax2i, 0, 8 * sizeof(int), stream);

  enc_kernel<<<512, 256, 0, stream>>>(x, enc_w1, enc_b1, enc_w2, enc_b2, enc_w3, enc_b3,
                                      latent, normed);
  pool_kernel<<<dim3(64, JC), 256, 0, stream>>>(normed, latent, p_acc, p_deg);
  pool_combine<<<512, 256, 0, stream>>>(latent, p_acc, p_deg, h);

  for (int blk = 0; blk < 2; ++blk) {
    qkv_kernel<<<128, 256, 0, stream>>>(h, wq + blk * 1024, bq + blk * 32,
                                        wk + blk * 1024, bk + blk * 32,
                                        wv + blk * 1024, bv + blk * 32, q, k, v,
                                        kmax2i + blk * 4);
    attn_kernel<<<dim3(64, JC), 256, 0, stream>>>(q, k, v, kmax2i + blk * 4, a_acc, a_l);
    acombine<<<512, 256, 0, stream>>>(a_acc, a_l, attno);
    oln1_kernel<<<128, 256, 0, stream>>>(attno, wo + blk * 1024, bo + blk * 32,
                                         ln1_g + blk * 32, ln1_b + blk * 32, h);
    ffn_kernel<<<128, 256, 0, stream>>>(h, ffn_w1 + blk * 2048, ffn_b1 + blk * 64,
                                        ffn_w2 + blk * 2048, ffn_b2 + blk * 32,
                                        ln2_g + blk * 32, ln2_b + blk * 32, h);
  }

  headp_kernel<<<64, 256, 0, stream>>>(h, partial);
  headf_kernel<<<1, 64, 0, stream>>>(partial, head_w1, head_b1, head_w2, head_b2, (float*)d_out);
}